// Round 1
// baseline (830.951 us; speedup 1.0000x reference)
//
#include <hip/hip_runtime.h>

// Problem constants
#define B 2
#define N_P 2000
#define N_ALL 2048          // N_P + N_S
#define N_REL 8192
#define N_HIS 4
#define N_INST 8
#define NF 128
#define IN_DIM 19
#define REL_DIM 56

// ---------------------------------------------------------------------------
// K0: extract receiver/sender indices from dense one-hot Rr/Rs.
// One wave per (matrix, b, r) row: scan 2048 floats, find the 1.0.
// This is the dominant HBM read (268 MB).
// ---------------------------------------------------------------------------
__global__ __launch_bounds__(256) void extract_idx(
    const float* __restrict__ Rr, const float* __restrict__ Rs,
    int* __restrict__ rr, int* __restrict__ rs)
{
    int gtid = blockIdx.x * 256 + threadIdx.x;
    int wid  = gtid >> 6;          // global wave id, 0..32767
    int lane = threadIdx.x & 63;
    int m = wid >> 14;             // 0 = Rr, 1 = Rs
    int e = wid & 16383;           // b*8192 + r
    const float* src = (m == 0 ? Rr : Rs) + (size_t)e * N_ALL;
    int found = -1;
    for (int i = lane * 4; i < N_ALL; i += 256) {
        float4 v = *reinterpret_cast<const float4*>(src + i);
        if (v.x > 0.5f) found = i;
        if (v.y > 0.5f) found = i + 1;
        if (v.z > 0.5f) found = i + 2;
        if (v.w > 0.5f) found = i + 3;
    }
    for (int off = 32; off; off >>= 1) found = max(found, __shfl_xor(found, off));
    if (lane == 0) (m == 0 ? rr : rs)[e] = found;
}

// ---------------------------------------------------------------------------
// K1: build p_inputs [B, N, 19] = attrs(2) | state_norm(12) | phys(1) | action(3) | den(1)
// ---------------------------------------------------------------------------
__global__ __launch_bounds__(256) void build_pinputs(
    const float* __restrict__ state, const float* __restrict__ attrs,
    const float* __restrict__ action, const float* __restrict__ den,
    const float* __restrict__ phys, float* __restrict__ P)
{
    int t = blockIdx.x * 256 + threadIdx.x;
    if (t >= B * N_ALL) return;
    int b = t >> 11, n = t & (N_ALL - 1);
    float* o = P + (size_t)t * IN_DIM;
    o[0] = attrs[t * 2];
    o[1] = attrs[t * 2 + 1];
    #pragma unroll
    for (int h = 0; h < 3; ++h)
        #pragma unroll
        for (int c = 0; c < 3; ++c)
            o[2 + h * 3 + c] = state[(((size_t)b * 4 + h + 1) * N_ALL + n) * 3 + c]
                             - state[(((size_t)b * 4 + h)     * N_ALL + n) * 3 + c];
    #pragma unroll
    for (int c = 0; c < 3; ++c)
        o[11 + c] = state[(((size_t)b * 4 + 3) * N_ALL + n) * 3 + c];
    o[14] = (n < N_P) ? phys[b] : 0.f;
    #pragma unroll
    for (int c = 0; c < 3; ++c) o[15 + c] = action[t * 3 + c];
    o[18] = (n < N_P) ? den[b] : 0.f;
}

// ---------------------------------------------------------------------------
// K2: build rel_inputs [B, 8192, 56] via index gathers
// p_r(19) | p_s(19) | a_r(2) | a_s(2) | group_diff(1) | pos_diff(12) | dens_diff(1)
// ---------------------------------------------------------------------------
__global__ __launch_bounds__(256) void build_relinputs(
    const float* __restrict__ P, const float* __restrict__ attrs,
    const float* __restrict__ p_inst,
    const int* __restrict__ rr, const int* __restrict__ rs,
    float* __restrict__ RI)
{
    int t = blockIdx.x * 256 + threadIdx.x;
    if (t >= B * N_REL) return;
    int b = t >> 13;
    int ir = rr[t], is_ = rs[t];
    const float* pr = P + ((size_t)b * N_ALL + ir) * IN_DIM;
    const float* ps = P + ((size_t)b * N_ALL + is_) * IN_DIM;
    float* o = RI + (size_t)t * REL_DIM;
    #pragma unroll
    for (int k = 0; k < IN_DIM; ++k) { o[k] = pr[k]; o[IN_DIM + k] = ps[k]; }
    o[38] = attrs[((size_t)b * N_ALL + ir) * 2];
    o[39] = attrs[((size_t)b * N_ALL + ir) * 2 + 1];
    o[40] = attrs[((size_t)b * N_ALL + is_) * 2];
    o[41] = attrs[((size_t)b * N_ALL + is_) * 2 + 1];
    float gd = 0.f;
    #pragma unroll
    for (int k = 0; k < N_INST; ++k) {
        float gr = (ir < N_P) ? p_inst[((size_t)b * N_P + ir) * N_INST + k] : 0.f;
        float gs = (is_ < N_P) ? p_inst[((size_t)b * N_P + is_) * N_INST + k] : 0.f;
        gd += fabsf(gr - gs);
    }
    o[42] = gd;
    #pragma unroll
    for (int k = 0; k < 12; ++k) o[43 + k] = pr[2 + k] - ps[2 + k];
    o[55] = pr[18] - ps[18];
}

// ---------------------------------------------------------------------------
// Generic tiled GEMM: Y[R,128] = act(X[R,K] @ W[K,128] + bias (+resid))
// Block: 256 threads, 64 rows x 128 cols, K-chunks of 32.
// MODE 0: plain X.  MODE 1: relation-propagator fused concat
//   [relation_encode | eff[rr] | eff[rs]]  (K=384).
// MODE 2: particle-propagator fused concat [particle_encode | agg] (K=256)
//   with residual add.
// ---------------------------------------------------------------------------
#define TR 64
#define KC 32

template<int MODE>
__global__ __launch_bounds__(256) void gemm_mlp(
    const float* __restrict__ X, const float* __restrict__ W,
    const float* __restrict__ bias, float* __restrict__ Y,
    int R, int K, int do_relu,
    const float* __restrict__ g0,   // MODE1: relation_encode ; MODE2: particle_encode
    const float* __restrict__ g1,   // MODE1: eff_in ; MODE2: agg
    const int* __restrict__ rr, const int* __restrict__ rs,
    const float* __restrict__ resid)
{
    __shared__ float sx[TR][KC + 1];
    __shared__ float sw[KC][NF];
    int t = threadIdx.x;
    int row0 = blockIdx.x * TR;
    int ty = t >> 4, tx = t & 15;      // 16x16 thread grid: 4 rows x 8 cols each
    float acc[4][8];
    #pragma unroll
    for (int i = 0; i < 4; ++i)
        #pragma unroll
        for (int j = 0; j < 8; ++j) acc[i][j] = 0.f;

    int nch = (K + KC - 1) / KC;
    for (int ch = 0; ch < nch; ++ch) {
        int k0 = ch * KC;
        // stage X tile (2048 elements)
        #pragma unroll
        for (int i = 0; i < 8; ++i) {
            int idx = t + 256 * i;
            int r = idx >> 5, kk = idx & 31;
            int row = row0 + r, k = k0 + kk;
            float v = 0.f;
            if (row < R && k < K) {
                if (MODE == 0) {
                    v = X[(size_t)row * K + k];
                } else if (MODE == 1) {
                    if (k < NF) v = g0[(size_t)row * NF + k];
                    else {
                        int b = row >> 13;
                        int node = (k < 2 * NF) ? rr[row] : rs[row];
                        v = g1[((size_t)b * N_ALL + node) * NF + (k & (NF - 1))];
                    }
                } else {
                    v = (k < NF) ? g0[(size_t)row * NF + k]
                                 : g1[(size_t)row * NF + (k - NF)];
                }
            }
            sx[r][kk] = v;
        }
        // stage W tile (4096 elements)
        #pragma unroll
        for (int i = 0; i < 16; ++i) {
            int idx = t + 256 * i;
            int kr = idx >> 7, c = idx & 127;
            int k = k0 + kr;
            sw[kr][c] = (k < K) ? W[(size_t)k * NF + c] : 0.f;
        }
        __syncthreads();
        #pragma unroll
        for (int kk = 0; kk < KC; ++kk) {
            float xv[4], wv[8];
            #pragma unroll
            for (int i = 0; i < 4; ++i) xv[i] = sx[ty * 4 + i][kk];
            #pragma unroll
            for (int j = 0; j < 8; ++j) wv[j] = sw[kk][tx * 8 + j];
            #pragma unroll
            for (int i = 0; i < 4; ++i)
                #pragma unroll
                for (int j = 0; j < 8; ++j) acc[i][j] += xv[i] * wv[j];
        }
        __syncthreads();
    }
    // epilogue
    #pragma unroll
    for (int i = 0; i < 4; ++i) {
        int row = row0 + ty * 4 + i;
        if (row >= R) continue;
        #pragma unroll
        for (int j = 0; j < 8; ++j) {
            int col = tx * 8 + j;
            float v = acc[i][j] + bias[col];
            if (MODE == 2) v += resid[(size_t)row * NF + col];
            if (do_relu) v = fmaxf(v, 0.f);
            Y[(size_t)row * NF + col] = v;
        }
    }
}

// ---------------------------------------------------------------------------
// Scatter-add: agg[b, rr[e], c] += effect_rel[b, e, c]
// ---------------------------------------------------------------------------
__global__ __launch_bounds__(256) void scatter_agg(
    const float* __restrict__ er, const int* __restrict__ rr,
    float* __restrict__ agg)
{
    int t = blockIdx.x * 256 + threadIdx.x;   // covers 2*8192*128
    int e = t >> 7, c = t & 127;
    int b = e >> 13;
    atomicAdd(&agg[((size_t)b * N_ALL + rr[e]) * NF + c], er[t]);
}

// ---------------------------------------------------------------------------
// Final predictor layer + clamp + residual position add
// ---------------------------------------------------------------------------
__global__ __launch_bounds__(256) void np_final(
    const float* __restrict__ h2, const float* __restrict__ W2,
    const float* __restrict__ b2, const float* __restrict__ state,
    float* __restrict__ out)
{
    int t = blockIdx.x * 256 + threadIdx.x;
    if (t >= B * N_P) return;
    int b = t / N_P, p = t % N_P;
    const float* hrow = h2 + ((size_t)b * N_ALL + p) * NF;
    #pragma unroll
    for (int j = 0; j < 3; ++j) {
        float s = b2[j];
        for (int k = 0; k < NF; ++k) s += hrow[k] * W2[k * 3 + j];
        s = fminf(fmaxf(s, -100.f), 100.f);
        out[(size_t)t * 3 + j] = s + state[(((size_t)b * 4 + 3) * N_ALL + p) * 3 + j];
    }
}

// ---------------------------------------------------------------------------
extern "C" void kernel_launch(void* const* d_in, const int* in_sizes, int n_in,
                              void* d_out, int out_size, void* d_ws, size_t ws_size,
                              hipStream_t stream) {
    (void)in_sizes; (void)n_in; (void)out_size; (void)ws_size;
    const float* state      = (const float*)d_in[0];
    const float* attrs      = (const float*)d_in[1];
    const float* Rr         = (const float*)d_in[2];
    const float* Rs         = (const float*)d_in[3];
    const float* p_instance = (const float*)d_in[4];
    const float* action     = (const float*)d_in[5];
    const float* den        = (const float*)d_in[6];
    const float* phys       = (const float*)d_in[7];
    const float* pe_W0 = (const float*)d_in[8];  const float* pe_b0 = (const float*)d_in[9];
    const float* pe_W1 = (const float*)d_in[10]; const float* pe_b1 = (const float*)d_in[11];
    const float* pe_W2 = (const float*)d_in[12]; const float* pe_b2 = (const float*)d_in[13];
    const float* re_W0 = (const float*)d_in[14]; const float* re_b0 = (const float*)d_in[15];
    const float* re_W1 = (const float*)d_in[16]; const float* re_b1 = (const float*)d_in[17];
    const float* re_W2 = (const float*)d_in[18]; const float* re_b2 = (const float*)d_in[19];
    const float* pp_W  = (const float*)d_in[20]; const float* pp_b  = (const float*)d_in[21];
    const float* rp_W  = (const float*)d_in[22]; const float* rp_b  = (const float*)d_in[23];
    const float* np_W0 = (const float*)d_in[24]; const float* np_b0 = (const float*)d_in[25];
    const float* np_W1 = (const float*)d_in[26]; const float* np_b1 = (const float*)d_in[27];
    const float* np_W2 = (const float*)d_in[28]; const float* np_b2 = (const float*)d_in[29];

    float* w = (float*)d_ws;
    size_t off = 0;
    int*   rr     = (int*)(w + off); off += B * N_REL;
    int*   rs     = (int*)(w + off); off += B * N_REL;
    float* P      = w + off; off += (size_t)B * N_ALL * IN_DIM;
    float* RI     = w + off; off += (size_t)B * N_REL * REL_DIM;
    float* relenc = w + off; off += (size_t)B * N_REL * NF;
    float* tA     = w + off; off += (size_t)B * N_REL * NF;   // tmp / effect_rel
    float* tB     = w + off; off += (size_t)B * N_REL * NF;   // tmp / agg
    float* penc   = w + off; off += (size_t)B * N_ALL * NF;
    float* effA   = w + off; off += (size_t)B * N_ALL * NF;
    float* effB   = w + off; off += (size_t)B * N_ALL * NF;

    const int RN = B * N_ALL;    // 4096 particle rows
    const int RE = B * N_REL;    // 16384 relation rows

    extract_idx<<<8192, 256, 0, stream>>>(Rr, Rs, rr, rs);
    build_pinputs<<<(RN + 255) / 256, 256, 0, stream>>>(state, attrs, action, den, phys, P);
    build_relinputs<<<(RE + 255) / 256, 256, 0, stream>>>(P, attrs, p_instance, rr, rs, RI);

    // particle encoder: 19 -> 128 -> 128 -> 128
    gemm_mlp<0><<<RN / TR, 256, 0, stream>>>(P,  pe_W0, pe_b0, tA,   RN, IN_DIM, 1, nullptr, nullptr, nullptr, nullptr, nullptr);
    gemm_mlp<0><<<RN / TR, 256, 0, stream>>>(tA, pe_W1, pe_b1, tB,   RN, NF,     1, nullptr, nullptr, nullptr, nullptr, nullptr);
    gemm_mlp<0><<<RN / TR, 256, 0, stream>>>(tB, pe_W2, pe_b2, penc, RN, NF,     1, nullptr, nullptr, nullptr, nullptr, nullptr);
    // relation encoder: 56 -> 128 -> 128 -> 128
    gemm_mlp<0><<<RE / TR, 256, 0, stream>>>(RI, re_W0, re_b0, tA,     RE, REL_DIM, 1, nullptr, nullptr, nullptr, nullptr, nullptr);
    gemm_mlp<0><<<RE / TR, 256, 0, stream>>>(tA, re_W1, re_b1, tB,     RE, NF,      1, nullptr, nullptr, nullptr, nullptr, nullptr);
    gemm_mlp<0><<<RE / TR, 256, 0, stream>>>(tB, re_W2, re_b2, relenc, RE, NF,      1, nullptr, nullptr, nullptr, nullptr, nullptr);

    // propagation steps
    const float* effin = penc;
    float* er  = tA;
    float* agg = tB;
    float* outbuf[3] = {effA, effB, effA};
    for (int s = 0; s < 3; ++s) {
        gemm_mlp<1><<<RE / TR, 256, 0, stream>>>(nullptr, rp_W, rp_b, er, RE, 3 * NF, 1,
                                                 relenc, effin, rr, rs, nullptr);
        hipMemsetAsync(agg, 0, (size_t)RN * NF * sizeof(float), stream);
        scatter_agg<<<(RE * NF) / 256, 256, 0, stream>>>(er, rr, agg);
        gemm_mlp<2><<<RN / TR, 256, 0, stream>>>(nullptr, pp_W, pp_b, outbuf[s], RN, 2 * NF, 1,
                                                 penc, agg, nullptr, nullptr, effin);
        effin = outbuf[s];
    }

    // predictor: 128 -> 128 -> 128 -> 3 (+clamp, +state)
    gemm_mlp<0><<<RN / TR, 256, 0, stream>>>(effin, np_W0, np_b0, tB, RN, NF, 1, nullptr, nullptr, nullptr, nullptr, nullptr);
    gemm_mlp<0><<<RN / TR, 256, 0, stream>>>(tB,    np_W1, np_b1, tA, RN, NF, 1, nullptr, nullptr, nullptr, nullptr, nullptr);
    np_final<<<(B * N_P + 255) / 256, 256, 0, stream>>>(tA, np_W2, np_b2, state, (float*)d_out);
}

// Round 2
// 179.529 us; speedup vs baseline: 4.6285x; 4.6285x over previous
//
#include <hip/hip_runtime.h>

#define B 2
#define N_P 2000
#define N_ALL 2048
#define N_REL 8192
#define N_INST 8
#define NF 128

typedef unsigned short u16;
typedef __attribute__((ext_vector_type(8))) short bf16x8;
typedef __attribute__((ext_vector_type(4))) float f32x4;

__device__ __forceinline__ u16 f2bf(float f) {
    union { float f; unsigned u; } v; v.f = f;
    unsigned r = v.u + 0x7FFFu + ((v.u >> 16) & 1u);
    return (u16)(r >> 16);
}
__device__ __forceinline__ float bf2f(u16 h) {
    union { unsigned u; float f; } v; v.u = ((unsigned)h) << 16; return v.f;
}

#define MFMA16(a, b, c) __builtin_amdgcn_mfma_f32_16x16x32_bf16((a), (b), (c), 0, 0, 0)

// ---------------------------------------------------------------------------
// K0: extract one-hot indices. One wave per row of Rr/Rs (268 MB HBM scan).
// ---------------------------------------------------------------------------
__global__ __launch_bounds__(256) void extract_idx(
    const float* __restrict__ Rr, const float* __restrict__ Rs,
    int* __restrict__ rr, int* __restrict__ rs)
{
    int gtid = blockIdx.x * 256 + threadIdx.x;
    int wid  = gtid >> 6;
    int lane = threadIdx.x & 63;
    int m = wid >> 14;
    int e = wid & 16383;
    const float* src = (m == 0 ? Rr : Rs) + (size_t)e * N_ALL;
    int found = -1;
    for (int i = lane * 4; i < N_ALL; i += 256) {
        float4 v = *reinterpret_cast<const float4*>(src + i);
        if (v.x > 0.5f) found = i;
        if (v.y > 0.5f) found = i + 1;
        if (v.z > 0.5f) found = i + 2;
        if (v.w > 0.5f) found = i + 3;
    }
    for (int off = 32; off; off >>= 1) found = max(found, __shfl_xor(found, off));
    if (lane == 0) (m == 0 ? rr : rs)[e] = found;
}

// ---------------------------------------------------------------------------
// K1: p_inputs -> bf16 padded [B*N_ALL][32]
// ---------------------------------------------------------------------------
__global__ __launch_bounds__(256) void build_pinputs(
    const float* __restrict__ state, const float* __restrict__ attrs,
    const float* __restrict__ action, const float* __restrict__ den,
    const float* __restrict__ phys, u16* __restrict__ P)
{
    int t = blockIdx.x * 256 + threadIdx.x;
    if (t >= B * N_ALL) return;
    int b = t >> 11, n = t & 2047;
    float o[19];
    o[0] = attrs[t * 2]; o[1] = attrs[t * 2 + 1];
    #pragma unroll
    for (int h = 0; h < 3; ++h)
        #pragma unroll
        for (int c = 0; c < 3; ++c)
            o[2 + h * 3 + c] = state[(((size_t)b * 4 + h + 1) * N_ALL + n) * 3 + c]
                             - state[(((size_t)b * 4 + h)     * N_ALL + n) * 3 + c];
    #pragma unroll
    for (int c = 0; c < 3; ++c)
        o[11 + c] = state[(((size_t)b * 4 + 3) * N_ALL + n) * 3 + c];
    o[14] = (n < N_P) ? phys[b] : 0.f;
    #pragma unroll
    for (int c = 0; c < 3; ++c) o[15 + c] = action[t * 3 + c];
    o[18] = (n < N_P) ? den[b] : 0.f;
    u16* dst = P + (size_t)t * 32;
    #pragma unroll
    for (int k = 0; k < 19; ++k) dst[k] = f2bf(o[k]);
    #pragma unroll
    for (int k = 19; k < 32; ++k) dst[k] = 0;
}

// ---------------------------------------------------------------------------
// K2: rel_inputs -> bf16 padded [B*N_REL][64]
// ---------------------------------------------------------------------------
__global__ __launch_bounds__(256) void build_relinputs(
    const u16* __restrict__ P, const float* __restrict__ attrs,
    const float* __restrict__ p_inst,
    const int* __restrict__ rr, const int* __restrict__ rs,
    u16* __restrict__ RI)
{
    int t = blockIdx.x * 256 + threadIdx.x;
    if (t >= B * N_REL) return;
    int b = t >> 13;
    int ir = rr[t], is_ = rs[t];
    const u16* pr = P + ((size_t)(b << 11) + ir) * 32;
    const u16* ps = P + ((size_t)(b << 11) + is_) * 32;
    u16* o = RI + (size_t)t * 64;
    #pragma unroll
    for (int k = 0; k < 19; ++k) { o[k] = pr[k]; o[19 + k] = ps[k]; }
    o[38] = f2bf(attrs[((size_t)(b << 11) + ir) * 2]);
    o[39] = f2bf(attrs[((size_t)(b << 11) + ir) * 2 + 1]);
    o[40] = f2bf(attrs[((size_t)(b << 11) + is_) * 2]);
    o[41] = f2bf(attrs[((size_t)(b << 11) + is_) * 2 + 1]);
    float gd = 0.f;
    #pragma unroll
    for (int k = 0; k < N_INST; ++k) {
        float gr = (ir < N_P) ? p_inst[((size_t)b * N_P + ir) * N_INST + k] : 0.f;
        float gs = (is_ < N_P) ? p_inst[((size_t)b * N_P + is_) * N_INST + k] : 0.f;
        gd += fabsf(gr - gs);
    }
    o[42] = f2bf(gd);
    #pragma unroll
    for (int k = 0; k < 12; ++k) o[43 + k] = f2bf(bf2f(pr[2 + k]) - bf2f(ps[2 + k]));
    o[55] = f2bf(bf2f(pr[18]) - bf2f(ps[18]));
    #pragma unroll
    for (int k = 56; k < 64; ++k) o[k] = 0;
}

// ---------------------------------------------------------------------------
// K3: weight convert fp32 [K][128] -> bf16 transposed padded [128][Kpad]
// ---------------------------------------------------------------------------
struct WtCvt {
    const float* src[10];
    int K[10];
    int Kpad[10];
    int cum[11];
};
__global__ __launch_bounds__(256) void cvt_wt(WtCvt d, u16* __restrict__ dst, int total)
{
    int t = blockIdx.x * 256 + threadIdx.x;
    if (t >= total) return;
    int m = 0;
    while (t >= d.cum[m + 1]) m++;
    int loc = t - d.cum[m];
    int Kp = d.Kpad[m];
    int c = loc / Kp, k = loc - c * Kp;
    float v = (k < d.K[m]) ? d.src[m][(size_t)k * NF + c] : 0.f;
    dst[t] = f2bf(v);
}

// ---------------------------------------------------------------------------
// Fused 3-layer encoder MLP (bf16 MFMA). Wave owns 16 rows x 128 cols.
// Inter-layer transpose through XOR-swizzled per-wave LDS tile (ping-pong).
// ---------------------------------------------------------------------------
template<int K0>
__global__ __launch_bounds__(256) void f_enc(
    const u16* __restrict__ X,
    const u16* __restrict__ wt0, const u16* __restrict__ wt1, const u16* __restrict__ wt2,
    const float* __restrict__ b0, const float* __restrict__ b1, const float* __restrict__ b2,
    u16* __restrict__ Y)
{
    __shared__ u16 tile[4][2][16 * NF];
    int w = threadIdx.x >> 6, lane = threadIdx.x & 63;
    int r16 = lane & 15, g4 = lane >> 4;
    int rbase = blockIdx.x * 64 + w * 16;
    f32x4 zero = {0.f, 0.f, 0.f, 0.f};
    f32x4 acc[8];

    // layer 0: from global X [rows][K0]
    #pragma unroll
    for (int cf = 0; cf < 8; ++cf) acc[cf] = zero;
    #pragma unroll
    for (int kf = 0; kf < K0 / 32; ++kf) {
        int kcol = kf * 32 + g4 * 8;
        bf16x8 a = *reinterpret_cast<const bf16x8*>(X + (size_t)(rbase + r16) * K0 + kcol);
        #pragma unroll
        for (int cf = 0; cf < 8; ++cf) {
            bf16x8 bv = *reinterpret_cast<const bf16x8*>(wt0 + (size_t)(cf * 16 + r16) * K0 + kcol);
            acc[cf] = MFMA16(a, bv, acc[cf]);
        }
    }
    // store relu(acc+b0) into tile 0 (swizzled)
    {
        u16* T = tile[w][0];
        #pragma unroll
        for (int cf = 0; cf < 8; ++cf) {
            float bv = b0[cf * 16 + r16];
            #pragma unroll
            for (int i = 0; i < 4; ++i) {
                int row = g4 * 4 + i, col = cf * 16 + r16;
                T[row * NF + (col ^ ((row & 7) << 3))] = f2bf(fmaxf(acc[cf][i] + bv, 0.f));
            }
        }
    }
    // layer 1: A from tile 0, store into tile 1
    {
        const u16* T = tile[w][0];
        #pragma unroll
        for (int cf = 0; cf < 8; ++cf) acc[cf] = zero;
        #pragma unroll
        for (int kf = 0; kf < 4; ++kf) {
            int kcol = kf * 32 + g4 * 8;
            bf16x8 a = *reinterpret_cast<const bf16x8*>(&T[r16 * NF + (kcol ^ ((r16 & 7) << 3))]);
            #pragma unroll
            for (int cf = 0; cf < 8; ++cf) {
                bf16x8 bv = *reinterpret_cast<const bf16x8*>(wt1 + (size_t)(cf * 16 + r16) * NF + kcol);
                acc[cf] = MFMA16(a, bv, acc[cf]);
            }
        }
        u16* T1 = tile[w][1];
        #pragma unroll
        for (int cf = 0; cf < 8; ++cf) {
            float bv = b1[cf * 16 + r16];
            #pragma unroll
            for (int i = 0; i < 4; ++i) {
                int row = g4 * 4 + i, col = cf * 16 + r16;
                T1[row * NF + (col ^ ((row & 7) << 3))] = f2bf(fmaxf(acc[cf][i] + bv, 0.f));
            }
        }
    }
    // layer 2: A from tile 1, write global Y
    {
        const u16* T = tile[w][1];
        #pragma unroll
        for (int cf = 0; cf < 8; ++cf) acc[cf] = zero;
        #pragma unroll
        for (int kf = 0; kf < 4; ++kf) {
            int kcol = kf * 32 + g4 * 8;
            bf16x8 a = *reinterpret_cast<const bf16x8*>(&T[r16 * NF + (kcol ^ ((r16 & 7) << 3))]);
            #pragma unroll
            for (int cf = 0; cf < 8; ++cf) {
                bf16x8 bv = *reinterpret_cast<const bf16x8*>(wt2 + (size_t)(cf * 16 + r16) * NF + kcol);
                acc[cf] = MFMA16(a, bv, acc[cf]);
            }
        }
        #pragma unroll
        for (int cf = 0; cf < 8; ++cf) {
            float bv = b2[cf * 16 + r16];
            #pragma unroll
            for (int i = 0; i < 4; ++i) {
                int row = rbase + g4 * 4 + i;
                Y[(size_t)row * NF + cf * 16 + r16] = f2bf(fmaxf(acc[cf][i] + bv, 0.f));
            }
        }
    }
}

// ---------------------------------------------------------------------------
// G1: relation propagator, K=384 = [relenc | eff[rr] | eff[rs]], fused scatter
// Wave owns 32 rows x 32 cols; no LDS, no barriers.
// ---------------------------------------------------------------------------
__global__ __launch_bounds__(256) void g1_rel(
    const u16* __restrict__ relenc, const u16* __restrict__ eff,
    const u16* __restrict__ wt_rp, const float* __restrict__ rp_b,
    const int* __restrict__ rr, const int* __restrict__ rs,
    float* __restrict__ agg)
{
    int lane = threadIdx.x & 63;
    int gw = blockIdx.x * 4 + (threadIdx.x >> 6);   // 2048 waves
    int rt = gw >> 2, ct = gw & 3;
    int r16 = lane & 15, g4 = lane >> 4;
    int rbase = rt * 32, cbase = ct * 32;

    int idxr[2], idxs[2];
    #pragma unroll
    for (int rf = 0; rf < 2; ++rf) {
        int row = rbase + rf * 16 + r16;
        int b = row >> 13;
        idxr[rf] = (b << 11) + rr[row];
        idxs[rf] = (b << 11) + rs[row];
    }
    f32x4 zero = {0.f, 0.f, 0.f, 0.f};
    f32x4 acc[2][2] = {{zero, zero}, {zero, zero}};

    #pragma unroll
    for (int kf = 0; kf < 12; ++kf) {
        int kcol = kf * 32 + g4 * 8;
        bf16x8 a[2];
        #pragma unroll
        for (int rf = 0; rf < 2; ++rf) {
            int row = rbase + rf * 16 + r16;
            const u16* ap;
            if (kf < 4)      ap = relenc + (size_t)row * NF + kcol;
            else if (kf < 8) ap = eff + (size_t)idxr[rf] * NF + (kcol - NF);
            else             ap = eff + (size_t)idxs[rf] * NF + (kcol - 2 * NF);
            a[rf] = *reinterpret_cast<const bf16x8*>(ap);
        }
        #pragma unroll
        for (int cf = 0; cf < 2; ++cf) {
            bf16x8 bv = *reinterpret_cast<const bf16x8*>(wt_rp + (size_t)(cbase + cf * 16 + r16) * 384 + kcol);
            #pragma unroll
            for (int rf = 0; rf < 2; ++rf)
                acc[rf][cf] = MFMA16(a[rf], bv, acc[rf][cf]);
        }
    }
    // epilogue: relu(acc + bias), atomic scatter into agg[rr[row]]
    #pragma unroll
    for (int rf = 0; rf < 2; ++rf)
        #pragma unroll
        for (int i = 0; i < 4; ++i) {
            int row = rbase + rf * 16 + g4 * 4 + i;
            int dstn = ((row >> 13) << 11) + rr[row];
            float* ap = agg + (size_t)dstn * NF;
            #pragma unroll
            for (int cf = 0; cf < 2; ++cf) {
                int col = cbase + cf * 16 + r16;
                float v = fmaxf(acc[rf][cf][i] + rp_b[col], 0.f);
                atomicAdd(ap + col, v);
            }
        }
}

// ---------------------------------------------------------------------------
// G2: particle propagator, K=256 = [penc | agg(fp32)], residual + relu
// ---------------------------------------------------------------------------
__global__ __launch_bounds__(256) void g2_part(
    const u16* __restrict__ penc, const float* __restrict__ agg,
    const u16* __restrict__ wt_pp, const float* __restrict__ pp_b,
    const u16* __restrict__ eff_prev, u16* __restrict__ eff_out)
{
    int lane = threadIdx.x & 63;
    int gw = blockIdx.x * 4 + (threadIdx.x >> 6);   // 512 waves
    int rt = gw >> 2, ct = gw & 3;
    int r16 = lane & 15, g4 = lane >> 4;
    int rbase = rt * 32, cbase = ct * 32;
    f32x4 zero = {0.f, 0.f, 0.f, 0.f};
    f32x4 acc[2][2] = {{zero, zero}, {zero, zero}};

    #pragma unroll
    for (int kf = 0; kf < 8; ++kf) {
        int kcol = kf * 32 + g4 * 8;
        bf16x8 a[2];
        #pragma unroll
        for (int rf = 0; rf < 2; ++rf) {
            int row = rbase + rf * 16 + r16;
            if (kf < 4) {
                a[rf] = *reinterpret_cast<const bf16x8*>(penc + (size_t)row * NF + kcol);
            } else {
                const float* ap = agg + (size_t)row * NF + (kcol - NF);
                float4 lo = *reinterpret_cast<const float4*>(ap);
                float4 hi = *reinterpret_cast<const float4*>(ap + 4);
                bf16x8 t;
                t[0] = (short)f2bf(lo.x); t[1] = (short)f2bf(lo.y);
                t[2] = (short)f2bf(lo.z); t[3] = (short)f2bf(lo.w);
                t[4] = (short)f2bf(hi.x); t[5] = (short)f2bf(hi.y);
                t[6] = (short)f2bf(hi.z); t[7] = (short)f2bf(hi.w);
                a[rf] = t;
            }
        }
        #pragma unroll
        for (int cf = 0; cf < 2; ++cf) {
            bf16x8 bv = *reinterpret_cast<const bf16x8*>(wt_pp + (size_t)(cbase + cf * 16 + r16) * 256 + kcol);
            #pragma unroll
            for (int rf = 0; rf < 2; ++rf)
                acc[rf][cf] = MFMA16(a[rf], bv, acc[rf][cf]);
        }
    }
    #pragma unroll
    for (int rf = 0; rf < 2; ++rf)
        #pragma unroll
        for (int i = 0; i < 4; ++i) {
            int row = rbase + rf * 16 + g4 * 4 + i;
            #pragma unroll
            for (int cf = 0; cf < 2; ++cf) {
                int col = cbase + cf * 16 + r16;
                float v = acc[rf][cf][i] + pp_b[col] + bf2f(eff_prev[(size_t)row * NF + col]);
                eff_out[(size_t)row * NF + col] = f2bf(fmaxf(v, 0.f));
            }
        }
}

// ---------------------------------------------------------------------------
// Fused predictor: np0 (MFMA) -> np1 (MFMA) -> np2 (128->3 dot) + clamp + state
// ---------------------------------------------------------------------------
__global__ __launch_bounds__(256) void f_np(
    const u16* __restrict__ eff,
    const u16* __restrict__ wt0, const u16* __restrict__ wt1,
    const float* __restrict__ b0, const float* __restrict__ b1,
    const float* __restrict__ W2, const float* __restrict__ b2,
    const float* __restrict__ state, float* __restrict__ out)
{
    __shared__ u16 tile[4][2][16 * NF];
    int w = threadIdx.x >> 6, lane = threadIdx.x & 63;
    int r16 = lane & 15, g4 = lane >> 4;
    int rbase = blockIdx.x * 64 + w * 16;
    f32x4 zero = {0.f, 0.f, 0.f, 0.f};
    f32x4 acc[8];

    // np0 from global eff
    #pragma unroll
    for (int cf = 0; cf < 8; ++cf) acc[cf] = zero;
    #pragma unroll
    for (int kf = 0; kf < 4; ++kf) {
        int kcol = kf * 32 + g4 * 8;
        bf16x8 a = *reinterpret_cast<const bf16x8*>(eff + (size_t)(rbase + r16) * NF + kcol);
        #pragma unroll
        for (int cf = 0; cf < 8; ++cf) {
            bf16x8 bv = *reinterpret_cast<const bf16x8*>(wt0 + (size_t)(cf * 16 + r16) * NF + kcol);
            acc[cf] = MFMA16(a, bv, acc[cf]);
        }
    }
    {
        u16* T = tile[w][0];
        #pragma unroll
        for (int cf = 0; cf < 8; ++cf) {
            float bv = b0[cf * 16 + r16];
            #pragma unroll
            for (int i = 0; i < 4; ++i) {
                int row = g4 * 4 + i, col = cf * 16 + r16;
                T[row * NF + (col ^ ((row & 7) << 3))] = f2bf(fmaxf(acc[cf][i] + bv, 0.f));
            }
        }
    }
    // np1 from tile0 -> tile1
    {
        const u16* T = tile[w][0];
        #pragma unroll
        for (int cf = 0; cf < 8; ++cf) acc[cf] = zero;
        #pragma unroll
        for (int kf = 0; kf < 4; ++kf) {
            int kcol = kf * 32 + g4 * 8;
            bf16x8 a = *reinterpret_cast<const bf16x8*>(&T[r16 * NF + (kcol ^ ((r16 & 7) << 3))]);
            #pragma unroll
            for (int cf = 0; cf < 8; ++cf) {
                bf16x8 bv = *reinterpret_cast<const bf16x8*>(wt1 + (size_t)(cf * 16 + r16) * NF + kcol);
                acc[cf] = MFMA16(a, bv, acc[cf]);
            }
        }
        u16* T1 = tile[w][1];
        #pragma unroll
        for (int cf = 0; cf < 8; ++cf) {
            float bv = b1[cf * 16 + r16];
            #pragma unroll
            for (int i = 0; i < 4; ++i) {
                int row = g4 * 4 + i, col = cf * 16 + r16;
                T1[row * NF + (col ^ ((row & 7) << 3))] = f2bf(fmaxf(acc[cf][i] + bv, 0.f));
            }
        }
    }
    // head: 3-col dot + clamp + residual state add
    if (g4 < 3) {
        const u16* T = tile[w][1];
        int grow = rbase + r16;
        int b = grow >> 11, n = grow & 2047;
        if (n < N_P) {
            float s = b2[g4];
            for (int k = 0; k < NF; ++k)
                s += bf2f(T[r16 * NF + (k ^ ((r16 & 7) << 3))]) * W2[k * 3 + g4];
            s = fminf(fmaxf(s, -100.f), 100.f);
            out[((size_t)b * N_P + n) * 3 + g4] =
                s + state[(((size_t)b * 4 + 3) * N_ALL + n) * 3 + g4];
        }
    }
}

// ---------------------------------------------------------------------------
extern "C" void kernel_launch(void* const* d_in, const int* in_sizes, int n_in,
                              void* d_out, int out_size, void* d_ws, size_t ws_size,
                              hipStream_t stream) {
    (void)in_sizes; (void)n_in; (void)out_size; (void)ws_size;
    const float* state      = (const float*)d_in[0];
    const float* attrs      = (const float*)d_in[1];
    const float* Rr         = (const float*)d_in[2];
    const float* Rs         = (const float*)d_in[3];
    const float* p_instance = (const float*)d_in[4];
    const float* action     = (const float*)d_in[5];
    const float* den        = (const float*)d_in[6];
    const float* phys       = (const float*)d_in[7];
    const float* pe_W0 = (const float*)d_in[8];  const float* pe_b0 = (const float*)d_in[9];
    const float* pe_W1 = (const float*)d_in[10]; const float* pe_b1 = (const float*)d_in[11];
    const float* pe_W2 = (const float*)d_in[12]; const float* pe_b2 = (const float*)d_in[13];
    const float* re_W0 = (const float*)d_in[14]; const float* re_b0 = (const float*)d_in[15];
    const float* re_W1 = (const float*)d_in[16]; const float* re_b1 = (const float*)d_in[17];
    const float* re_W2 = (const float*)d_in[18]; const float* re_b2 = (const float*)d_in[19];
    const float* pp_W  = (const float*)d_in[20]; const float* pp_b  = (const float*)d_in[21];
    const float* rp_W  = (const float*)d_in[22]; const float* rp_b  = (const float*)d_in[23];
    const float* np_W0 = (const float*)d_in[24]; const float* np_b0 = (const float*)d_in[25];
    const float* np_W1 = (const float*)d_in[26]; const float* np_b1 = (const float*)d_in[27];
    const float* np_W2 = (const float*)d_in[28]; const float* np_b2 = (const float*)d_in[29];

    char* base = (char*)d_ws;
    size_t off = 0;
    auto alloc = [&](size_t bytes) -> void* {
        off = (off + 255) & ~(size_t)255;
        void* p = base + off; off += bytes; return p;
    };
    int* rr      = (int*)alloc(B * N_REL * 4);
    int* rs      = (int*)alloc(B * N_REL * 4);
    u16* P       = (u16*)alloc((size_t)B * N_ALL * 32 * 2);
    u16* RI      = (u16*)alloc((size_t)B * N_REL * 64 * 2);
    u16* penc    = (u16*)alloc((size_t)B * N_ALL * NF * 2);
    u16* relenc  = (u16*)alloc((size_t)B * N_REL * NF * 2);
    u16* effA    = (u16*)alloc((size_t)B * N_ALL * NF * 2);
    u16* effB    = (u16*)alloc((size_t)B * N_ALL * NF * 2);
    float* agg   = (float*)alloc((size_t)B * N_ALL * NF * 4);

    WtCvt d;
    const float* srcs[10] = {pe_W0, pe_W1, pe_W2, re_W0, re_W1, re_W2, pp_W, rp_W, np_W0, np_W1};
    const int Ks[10]  = {19, 128, 128, 56, 128, 128, 256, 384, 128, 128};
    const int Kps[10] = {32, 128, 128, 64, 128, 128, 256, 384, 128, 128};
    d.cum[0] = 0;
    for (int i = 0; i < 10; ++i) {
        d.src[i] = srcs[i]; d.K[i] = Ks[i]; d.Kpad[i] = Kps[i];
        d.cum[i + 1] = d.cum[i] + NF * Kps[i];
    }
    int wt_total = d.cum[10];
    u16* wt = (u16*)alloc((size_t)wt_total * 2);

    const int RN = B * N_ALL;    // 4096
    const int RE = B * N_REL;    // 16384

    extract_idx<<<8192, 256, 0, stream>>>(Rr, Rs, rr, rs);
    cvt_wt<<<(wt_total + 255) / 256, 256, 0, stream>>>(d, wt, wt_total);
    build_pinputs<<<(RN + 255) / 256, 256, 0, stream>>>(state, attrs, action, den, phys, P);
    build_relinputs<<<(RE + 255) / 256, 256, 0, stream>>>(P, attrs, p_instance, rr, rs, RI);

    f_enc<32><<<RN / 64, 256, 0, stream>>>(P, wt + d.cum[0], wt + d.cum[1], wt + d.cum[2],
                                           pe_b0, pe_b1, pe_b2, penc);
    f_enc<64><<<RE / 64, 256, 0, stream>>>(RI, wt + d.cum[3], wt + d.cum[4], wt + d.cum[5],
                                           re_b0, re_b1, re_b2, relenc);

    const u16* effin = penc;
    u16* outbuf[3] = {effA, effB, effA};
    for (int s = 0; s < 3; ++s) {
        hipMemsetAsync(agg, 0, (size_t)RN * NF * 4, stream);
        g1_rel<<<RE / 32, 256, 0, stream>>>(relenc, effin, wt + d.cum[7], rp_b, rr, rs, agg);
        g2_part<<<RN / 32, 256, 0, stream>>>(penc, agg, wt + d.cum[6], pp_b, effin, outbuf[s]);
        effin = outbuf[s];
    }

    f_np<<<RN / 64, 256, 0, stream>>>(effin, wt + d.cum[8], wt + d.cum[9],
                                      np_b0, np_b1, np_W2, np_b2, state, (float*)d_out);
}

// Round 3
// 169.285 us; speedup vs baseline: 4.9086x; 1.0605x over previous
//
#include <hip/hip_runtime.h>

#define B 2
#define N_P 2000
#define N_ALL 2048
#define N_REL 8192
#define N_INST 8
#define NF 128

typedef unsigned short u16;
typedef __attribute__((ext_vector_type(8))) short bf16x8;
typedef __attribute__((ext_vector_type(4))) float f32x4;

__device__ __forceinline__ u16 f2bf(float f) {
    union { float f; unsigned u; } v; v.f = f;
    unsigned r = v.u + 0x7FFFu + ((v.u >> 16) & 1u);
    return (u16)(r >> 16);
}
__device__ __forceinline__ float bf2f(u16 h) {
    union { unsigned u; float f; } v; v.u = ((unsigned)h) << 16; return v.f;
}

#define MFMA16(a, b, c) __builtin_amdgcn_mfma_f32_16x16x32_bf16((a), (b), (c), 0, 0, 0)

// weight-convert descriptor
struct WtCvt {
    const float* src[10];
    int K[10];
    int Kpad[10];
    int cum[11];
};

// ---------------------------------------------------------------------------
// PREP kernel: block-ranged fusion of 4 independent jobs.
//   blocks [0, 8192):            one-hot index extraction (268 MB HBM scan),
//                                8 float4 loads in flight per lane (MLP fix)
//   blocks [8192, 8944):         weight convert fp32 [K][128] -> bf16 [128][Kpad]
//   blocks [8944, 8960):         build p_inputs bf16 [B*N_ALL][32]
//   blocks [8960, 10496):        zero 3 agg buffers (float4 stores)
// ---------------------------------------------------------------------------
#define PREP_EXTRACT_BLKS 8192
#define PREP_CVT_BLKS     752
#define PREP_PIN_BLKS     16
#define PREP_ZERO_BLKS    1536
#define PREP_TOTAL (PREP_EXTRACT_BLKS + PREP_CVT_BLKS + PREP_PIN_BLKS + PREP_ZERO_BLKS)

__global__ __launch_bounds__(256) void prep(
    const float* __restrict__ Rr, const float* __restrict__ Rs,
    int* __restrict__ rr, int* __restrict__ rs,
    WtCvt d, u16* __restrict__ wt, int wt_total,
    const float* __restrict__ state, const float* __restrict__ attrs,
    const float* __restrict__ action, const float* __restrict__ den,
    const float* __restrict__ phys, u16* __restrict__ P,
    float* __restrict__ aggz, int aggz_f4)   // 3 agg buffers, contiguous, in float4s
{
    int blk = blockIdx.x;
    if (blk < PREP_EXTRACT_BLKS) {
        // ---- one-hot index extraction, wave per row ----
        int wid = (blk << 2) + (threadIdx.x >> 6);   // 0..32767
        int lane = threadIdx.x & 63;
        int m = wid >> 14;                            // 0 = Rr, 1 = Rs
        int e = wid & 16383;
        const float4* src = reinterpret_cast<const float4*>(
            (m == 0 ? Rr : Rs) + (size_t)e * N_ALL);
        float4 v[8];
        #pragma unroll
        for (int i = 0; i < 8; ++i) v[i] = src[lane + 64 * i];
        int found = -1;
        #pragma unroll
        for (int i = 0; i < 8; ++i) {
            int basei = (lane + 64 * i) * 4;
            if (v[i].x != 0.f) found = basei;
            if (v[i].y != 0.f) found = basei + 1;
            if (v[i].z != 0.f) found = basei + 2;
            if (v[i].w != 0.f) found = basei + 3;
        }
        #pragma unroll
        for (int off = 32; off; off >>= 1) found = max(found, __shfl_xor(found, off));
        if (lane == 0) (m == 0 ? rr : rs)[e] = found;
        return;
    }
    blk -= PREP_EXTRACT_BLKS;
    if (blk < PREP_CVT_BLKS) {
        // ---- weight convert ----
        int t = blk * 256 + threadIdx.x;
        if (t >= wt_total) return;
        int m = 0;
        while (t >= d.cum[m + 1]) m++;
        int loc = t - d.cum[m];
        int Kp = d.Kpad[m];
        int c = loc / Kp, k = loc - c * Kp;
        float v = (k < d.K[m]) ? d.src[m][(size_t)k * NF + c] : 0.f;
        wt[t] = f2bf(v);
        return;
    }
    blk -= PREP_CVT_BLKS;
    if (blk < PREP_PIN_BLKS) {
        // ---- build p_inputs ----
        int t = blk * 256 + threadIdx.x;
        if (t >= B * N_ALL) return;
        int b = t >> 11, n = t & 2047;
        float o[19];
        o[0] = attrs[t * 2]; o[1] = attrs[t * 2 + 1];
        #pragma unroll
        for (int h = 0; h < 3; ++h)
            #pragma unroll
            for (int c = 0; c < 3; ++c)
                o[2 + h * 3 + c] = state[(((size_t)b * 4 + h + 1) * N_ALL + n) * 3 + c]
                                 - state[(((size_t)b * 4 + h)     * N_ALL + n) * 3 + c];
        #pragma unroll
        for (int c = 0; c < 3; ++c)
            o[11 + c] = state[(((size_t)b * 4 + 3) * N_ALL + n) * 3 + c];
        o[14] = (n < N_P) ? phys[b] : 0.f;
        #pragma unroll
        for (int c = 0; c < 3; ++c) o[15 + c] = action[t * 3 + c];
        o[18] = (n < N_P) ? den[b] : 0.f;
        u16* dst = P + (size_t)t * 32;
        #pragma unroll
        for (int k = 0; k < 19; ++k) dst[k] = f2bf(o[k]);
        #pragma unroll
        for (int k = 19; k < 32; ++k) dst[k] = 0;
        return;
    }
    blk -= PREP_PIN_BLKS;
    {
        // ---- zero agg buffers ----
        int t = blk * 256 + threadIdx.x;
        if (t < aggz_f4) {
            float4 z = {0.f, 0.f, 0.f, 0.f};
            reinterpret_cast<float4*>(aggz)[t] = z;
        }
    }
}

// ---------------------------------------------------------------------------
// K2: rel_inputs -> bf16 padded [B*N_REL][64]
// ---------------------------------------------------------------------------
__global__ __launch_bounds__(256) void build_relinputs(
    const u16* __restrict__ P, const float* __restrict__ attrs,
    const float* __restrict__ p_inst,
    const int* __restrict__ rr, const int* __restrict__ rs,
    u16* __restrict__ RI)
{
    int t = blockIdx.x * 256 + threadIdx.x;
    if (t >= B * N_REL) return;
    int b = t >> 13;
    int ir = rr[t], is_ = rs[t];
    const u16* pr = P + ((size_t)(b << 11) + ir) * 32;
    const u16* ps = P + ((size_t)(b << 11) + is_) * 32;
    u16* o = RI + (size_t)t * 64;
    #pragma unroll
    for (int k = 0; k < 19; ++k) { o[k] = pr[k]; o[19 + k] = ps[k]; }
    o[38] = f2bf(attrs[((size_t)(b << 11) + ir) * 2]);
    o[39] = f2bf(attrs[((size_t)(b << 11) + ir) * 2 + 1]);
    o[40] = f2bf(attrs[((size_t)(b << 11) + is_) * 2]);
    o[41] = f2bf(attrs[((size_t)(b << 11) + is_) * 2 + 1]);
    float gd = 0.f;
    #pragma unroll
    for (int k = 0; k < N_INST; ++k) {
        float gr = (ir < N_P) ? p_inst[((size_t)b * N_P + ir) * N_INST + k] : 0.f;
        float gs = (is_ < N_P) ? p_inst[((size_t)b * N_P + is_) * N_INST + k] : 0.f;
        gd += fabsf(gr - gs);
    }
    o[42] = f2bf(gd);
    #pragma unroll
    for (int k = 0; k < 12; ++k) o[43 + k] = f2bf(bf2f(pr[2 + k]) - bf2f(ps[2 + k]));
    o[55] = f2bf(bf2f(pr[18]) - bf2f(ps[18]));
    #pragma unroll
    for (int k = 56; k < 64; ++k) o[k] = 0;
}

// ---------------------------------------------------------------------------
// Fused 3-layer encoder MLP (bf16 MFMA). Wave owns 16 rows x 128 cols.
// ---------------------------------------------------------------------------
template<int K0>
__global__ __launch_bounds__(256) void f_enc(
    const u16* __restrict__ X,
    const u16* __restrict__ wt0, const u16* __restrict__ wt1, const u16* __restrict__ wt2,
    const float* __restrict__ b0, const float* __restrict__ b1, const float* __restrict__ b2,
    u16* __restrict__ Y)
{
    __shared__ u16 tile[4][2][16 * NF];
    int w = threadIdx.x >> 6, lane = threadIdx.x & 63;
    int r16 = lane & 15, g4 = lane >> 4;
    int rbase = blockIdx.x * 64 + w * 16;
    f32x4 zero = {0.f, 0.f, 0.f, 0.f};
    f32x4 acc[8];

    #pragma unroll
    for (int cf = 0; cf < 8; ++cf) acc[cf] = zero;
    #pragma unroll
    for (int kf = 0; kf < K0 / 32; ++kf) {
        int kcol = kf * 32 + g4 * 8;
        bf16x8 a = *reinterpret_cast<const bf16x8*>(X + (size_t)(rbase + r16) * K0 + kcol);
        #pragma unroll
        for (int cf = 0; cf < 8; ++cf) {
            bf16x8 bv = *reinterpret_cast<const bf16x8*>(wt0 + (size_t)(cf * 16 + r16) * K0 + kcol);
            acc[cf] = MFMA16(a, bv, acc[cf]);
        }
    }
    {
        u16* T = tile[w][0];
        #pragma unroll
        for (int cf = 0; cf < 8; ++cf) {
            float bv = b0[cf * 16 + r16];
            #pragma unroll
            for (int i = 0; i < 4; ++i) {
                int row = g4 * 4 + i, col = cf * 16 + r16;
                T[row * NF + (col ^ ((row & 7) << 3))] = f2bf(fmaxf(acc[cf][i] + bv, 0.f));
            }
        }
    }
    {
        const u16* T = tile[w][0];
        #pragma unroll
        for (int cf = 0; cf < 8; ++cf) acc[cf] = zero;
        #pragma unroll
        for (int kf = 0; kf < 4; ++kf) {
            int kcol = kf * 32 + g4 * 8;
            bf16x8 a = *reinterpret_cast<const bf16x8*>(&T[r16 * NF + (kcol ^ ((r16 & 7) << 3))]);
            #pragma unroll
            for (int cf = 0; cf < 8; ++cf) {
                bf16x8 bv = *reinterpret_cast<const bf16x8*>(wt1 + (size_t)(cf * 16 + r16) * NF + kcol);
                acc[cf] = MFMA16(a, bv, acc[cf]);
            }
        }
        u16* T1 = tile[w][1];
        #pragma unroll
        for (int cf = 0; cf < 8; ++cf) {
            float bv = b1[cf * 16 + r16];
            #pragma unroll
            for (int i = 0; i < 4; ++i) {
                int row = g4 * 4 + i, col = cf * 16 + r16;
                T1[row * NF + (col ^ ((row & 7) << 3))] = f2bf(fmaxf(acc[cf][i] + bv, 0.f));
            }
        }
    }
    {
        const u16* T = tile[w][1];
        #pragma unroll
        for (int cf = 0; cf < 8; ++cf) acc[cf] = zero;
        #pragma unroll
        for (int kf = 0; kf < 4; ++kf) {
            int kcol = kf * 32 + g4 * 8;
            bf16x8 a = *reinterpret_cast<const bf16x8*>(&T[r16 * NF + (kcol ^ ((r16 & 7) << 3))]);
            #pragma unroll
            for (int cf = 0; cf < 8; ++cf) {
                bf16x8 bv = *reinterpret_cast<const bf16x8*>(wt2 + (size_t)(cf * 16 + r16) * NF + kcol);
                acc[cf] = MFMA16(a, bv, acc[cf]);
            }
        }
        #pragma unroll
        for (int cf = 0; cf < 8; ++cf) {
            float bv = b2[cf * 16 + r16];
            #pragma unroll
            for (int i = 0; i < 4; ++i) {
                int row = rbase + g4 * 4 + i;
                Y[(size_t)row * NF + cf * 16 + r16] = f2bf(fmaxf(acc[cf][i] + bv, 0.f));
            }
        }
    }
}

// ---------------------------------------------------------------------------
// G1: relation propagator, K=384 = [relenc | eff[rr] | eff[rs]], fused scatter
// ---------------------------------------------------------------------------
__global__ __launch_bounds__(256) void g1_rel(
    const u16* __restrict__ relenc, const u16* __restrict__ eff,
    const u16* __restrict__ wt_rp, const float* __restrict__ rp_b,
    const int* __restrict__ rr, const int* __restrict__ rs,
    float* __restrict__ agg)
{
    int lane = threadIdx.x & 63;
    int gw = blockIdx.x * 4 + (threadIdx.x >> 6);
    int rt = gw >> 2, ct = gw & 3;
    int r16 = lane & 15, g4 = lane >> 4;
    int rbase = rt * 32, cbase = ct * 32;

    int idxr[2], idxs[2];
    #pragma unroll
    for (int rf = 0; rf < 2; ++rf) {
        int row = rbase + rf * 16 + r16;
        int b = row >> 13;
        idxr[rf] = (b << 11) + rr[row];
        idxs[rf] = (b << 11) + rs[row];
    }
    f32x4 zero = {0.f, 0.f, 0.f, 0.f};
    f32x4 acc[2][2] = {{zero, zero}, {zero, zero}};

    #pragma unroll
    for (int kf = 0; kf < 12; ++kf) {
        int kcol = kf * 32 + g4 * 8;
        bf16x8 a[2];
        #pragma unroll
        for (int rf = 0; rf < 2; ++rf) {
            int row = rbase + rf * 16 + r16;
            const u16* ap;
            if (kf < 4)      ap = relenc + (size_t)row * NF + kcol;
            else if (kf < 8) ap = eff + (size_t)idxr[rf] * NF + (kcol - NF);
            else             ap = eff + (size_t)idxs[rf] * NF + (kcol - 2 * NF);
            a[rf] = *reinterpret_cast<const bf16x8*>(ap);
        }
        #pragma unroll
        for (int cf = 0; cf < 2; ++cf) {
            bf16x8 bv = *reinterpret_cast<const bf16x8*>(wt_rp + (size_t)(cbase + cf * 16 + r16) * 384 + kcol);
            #pragma unroll
            for (int rf = 0; rf < 2; ++rf)
                acc[rf][cf] = MFMA16(a[rf], bv, acc[rf][cf]);
        }
    }
    #pragma unroll
    for (int rf = 0; rf < 2; ++rf)
        #pragma unroll
        for (int i = 0; i < 4; ++i) {
            int row = rbase + rf * 16 + g4 * 4 + i;
            int dstn = ((row >> 13) << 11) + rr[row];
            float* ap = agg + (size_t)dstn * NF;
            #pragma unroll
            for (int cf = 0; cf < 2; ++cf) {
                int col = cbase + cf * 16 + r16;
                float v = fmaxf(acc[rf][cf][i] + rp_b[col], 0.f);
                atomicAdd(ap + col, v);
            }
        }
}

// ---------------------------------------------------------------------------
// G2: particle propagator, K=256 = [penc | agg(fp32)], residual + relu
// ---------------------------------------------------------------------------
__global__ __launch_bounds__(256) void g2_part(
    const u16* __restrict__ penc, const float* __restrict__ agg,
    const u16* __restrict__ wt_pp, const float* __restrict__ pp_b,
    const u16* __restrict__ eff_prev, u16* __restrict__ eff_out)
{
    int lane = threadIdx.x & 63;
    int gw = blockIdx.x * 4 + (threadIdx.x >> 6);
    int rt = gw >> 2, ct = gw & 3;
    int r16 = lane & 15, g4 = lane >> 4;
    int rbase = rt * 32, cbase = ct * 32;
    f32x4 zero = {0.f, 0.f, 0.f, 0.f};
    f32x4 acc[2][2] = {{zero, zero}, {zero, zero}};

    #pragma unroll
    for (int kf = 0; kf < 8; ++kf) {
        int kcol = kf * 32 + g4 * 8;
        bf16x8 a[2];
        #pragma unroll
        for (int rf = 0; rf < 2; ++rf) {
            int row = rbase + rf * 16 + r16;
            if (kf < 4) {
                a[rf] = *reinterpret_cast<const bf16x8*>(penc + (size_t)row * NF + kcol);
            } else {
                const float* ap = agg + (size_t)row * NF + (kcol - NF);
                float4 lo = *reinterpret_cast<const float4*>(ap);
                float4 hi = *reinterpret_cast<const float4*>(ap + 4);
                bf16x8 t;
                t[0] = (short)f2bf(lo.x); t[1] = (short)f2bf(lo.y);
                t[2] = (short)f2bf(lo.z); t[3] = (short)f2bf(lo.w);
                t[4] = (short)f2bf(hi.x); t[5] = (short)f2bf(hi.y);
                t[6] = (short)f2bf(hi.z); t[7] = (short)f2bf(hi.w);
                a[rf] = t;
            }
        }
        #pragma unroll
        for (int cf = 0; cf < 2; ++cf) {
            bf16x8 bv = *reinterpret_cast<const bf16x8*>(wt_pp + (size_t)(cbase + cf * 16 + r16) * 256 + kcol);
            #pragma unroll
            for (int rf = 0; rf < 2; ++rf)
                acc[rf][cf] = MFMA16(a[rf], bv, acc[rf][cf]);
        }
    }
    #pragma unroll
    for (int rf = 0; rf < 2; ++rf)
        #pragma unroll
        for (int i = 0; i < 4; ++i) {
            int row = rbase + rf * 16 + g4 * 4 + i;
            #pragma unroll
            for (int cf = 0; cf < 2; ++cf) {
                int col = cbase + cf * 16 + r16;
                float v = acc[rf][cf][i] + pp_b[col] + bf2f(eff_prev[(size_t)row * NF + col]);
                eff_out[(size_t)row * NF + col] = f2bf(fmaxf(v, 0.f));
            }
        }
}

// ---------------------------------------------------------------------------
// Fused predictor: np0 -> np1 -> np2 + clamp + state residual
// ---------------------------------------------------------------------------
__global__ __launch_bounds__(256) void f_np(
    const u16* __restrict__ eff,
    const u16* __restrict__ wt0, const u16* __restrict__ wt1,
    const float* __restrict__ b0, const float* __restrict__ b1,
    const float* __restrict__ W2, const float* __restrict__ b2,
    const float* __restrict__ state, float* __restrict__ out)
{
    __shared__ u16 tile[4][2][16 * NF];
    int w = threadIdx.x >> 6, lane = threadIdx.x & 63;
    int r16 = lane & 15, g4 = lane >> 4;
    int rbase = blockIdx.x * 64 + w * 16;
    f32x4 zero = {0.f, 0.f, 0.f, 0.f};
    f32x4 acc[8];

    #pragma unroll
    for (int cf = 0; cf < 8; ++cf) acc[cf] = zero;
    #pragma unroll
    for (int kf = 0; kf < 4; ++kf) {
        int kcol = kf * 32 + g4 * 8;
        bf16x8 a = *reinterpret_cast<const bf16x8*>(eff + (size_t)(rbase + r16) * NF + kcol);
        #pragma unroll
        for (int cf = 0; cf < 8; ++cf) {
            bf16x8 bv = *reinterpret_cast<const bf16x8*>(wt0 + (size_t)(cf * 16 + r16) * NF + kcol);
            acc[cf] = MFMA16(a, bv, acc[cf]);
        }
    }
    {
        u16* T = tile[w][0];
        #pragma unroll
        for (int cf = 0; cf < 8; ++cf) {
            float bv = b0[cf * 16 + r16];
            #pragma unroll
            for (int i = 0; i < 4; ++i) {
                int row = g4 * 4 + i, col = cf * 16 + r16;
                T[row * NF + (col ^ ((row & 7) << 3))] = f2bf(fmaxf(acc[cf][i] + bv, 0.f));
            }
        }
    }
    {
        const u16* T = tile[w][0];
        #pragma unroll
        for (int cf = 0; cf < 8; ++cf) acc[cf] = zero;
        #pragma unroll
        for (int kf = 0; kf < 4; ++kf) {
            int kcol = kf * 32 + g4 * 8;
            bf16x8 a = *reinterpret_cast<const bf16x8*>(&T[r16 * NF + (kcol ^ ((r16 & 7) << 3))]);
            #pragma unroll
            for (int cf = 0; cf < 8; ++cf) {
                bf16x8 bv = *reinterpret_cast<const bf16x8*>(wt1 + (size_t)(cf * 16 + r16) * NF + kcol);
                acc[cf] = MFMA16(a, bv, acc[cf]);
            }
        }
        u16* T1 = tile[w][1];
        #pragma unroll
        for (int cf = 0; cf < 8; ++cf) {
            float bv = b1[cf * 16 + r16];
            #pragma unroll
            for (int i = 0; i < 4; ++i) {
                int row = g4 * 4 + i, col = cf * 16 + r16;
                T1[row * NF + (col ^ ((row & 7) << 3))] = f2bf(fmaxf(acc[cf][i] + bv, 0.f));
            }
        }
    }
    if (g4 < 3) {
        const u16* T = tile[w][1];
        int grow = rbase + r16;
        int b = grow >> 11, n = grow & 2047;
        if (n < N_P) {
            float s = b2[g4];
            for (int k = 0; k < NF; ++k)
                s += bf2f(T[r16 * NF + (k ^ ((r16 & 7) << 3))]) * W2[k * 3 + g4];
            s = fminf(fmaxf(s, -100.f), 100.f);
            out[((size_t)b * N_P + n) * 3 + g4] =
                s + state[(((size_t)b * 4 + 3) * N_ALL + n) * 3 + g4];
        }
    }
}

// ---------------------------------------------------------------------------
extern "C" void kernel_launch(void* const* d_in, const int* in_sizes, int n_in,
                              void* d_out, int out_size, void* d_ws, size_t ws_size,
                              hipStream_t stream) {
    (void)in_sizes; (void)n_in; (void)out_size; (void)ws_size;
    const float* state      = (const float*)d_in[0];
    const float* attrs      = (const float*)d_in[1];
    const float* Rr         = (const float*)d_in[2];
    const float* Rs         = (const float*)d_in[3];
    const float* p_instance = (const float*)d_in[4];
    const float* action     = (const float*)d_in[5];
    const float* den        = (const float*)d_in[6];
    const float* phys       = (const float*)d_in[7];
    const float* pe_W0 = (const float*)d_in[8];  const float* pe_b0 = (const float*)d_in[9];
    const float* pe_W1 = (const float*)d_in[10]; const float* pe_b1 = (const float*)d_in[11];
    const float* pe_W2 = (const float*)d_in[12]; const float* pe_b2 = (const float*)d_in[13];
    const float* re_W0 = (const float*)d_in[14]; const float* re_b0 = (const float*)d_in[15];
    const float* re_W1 = (const float*)d_in[16]; const float* re_b1 = (const float*)d_in[17];
    const float* re_W2 = (const float*)d_in[18]; const float* re_b2 = (const float*)d_in[19];
    const float* pp_W  = (const float*)d_in[20]; const float* pp_b  = (const float*)d_in[21];
    const float* rp_W  = (const float*)d_in[22]; const float* rp_b  = (const float*)d_in[23];
    const float* np_W0 = (const float*)d_in[24]; const float* np_b0 = (const float*)d_in[25];
    const float* np_W1 = (const float*)d_in[26]; const float* np_b1 = (const float*)d_in[27];
    const float* np_W2 = (const float*)d_in[28]; const float* np_b2 = (const float*)d_in[29];

    char* base = (char*)d_ws;
    size_t off = 0;
    auto alloc = [&](size_t bytes) -> void* {
        off = (off + 255) & ~(size_t)255;
        void* p = base + off; off += bytes; return p;
    };
    int* rr      = (int*)alloc(B * N_REL * 4);
    int* rs      = (int*)alloc(B * N_REL * 4);
    u16* P       = (u16*)alloc((size_t)B * N_ALL * 32 * 2);
    u16* RI      = (u16*)alloc((size_t)B * N_REL * 64 * 2);
    u16* penc    = (u16*)alloc((size_t)B * N_ALL * NF * 2);
    u16* relenc  = (u16*)alloc((size_t)B * N_REL * NF * 2);
    u16* effA    = (u16*)alloc((size_t)B * N_ALL * NF * 2);
    u16* effB    = (u16*)alloc((size_t)B * N_ALL * NF * 2);
    float* agg3  = (float*)alloc((size_t)3 * B * N_ALL * NF * 4);  // 3 step-private aggs

    WtCvt d;
    const float* srcs[10] = {pe_W0, pe_W1, pe_W2, re_W0, re_W1, re_W2, pp_W, rp_W, np_W0, np_W1};
    const int Ks[10]  = {19, 128, 128, 56, 128, 128, 256, 384, 128, 128};
    const int Kps[10] = {32, 128, 128, 64, 128, 128, 256, 384, 128, 128};
    d.cum[0] = 0;
    for (int i = 0; i < 10; ++i) {
        d.src[i] = srcs[i]; d.K[i] = Ks[i]; d.Kpad[i] = Kps[i];
        d.cum[i + 1] = d.cum[i] + NF * Kps[i];
    }
    int wt_total = d.cum[10];
    u16* wt = (u16*)alloc((size_t)wt_total * 2);

    const int RN = B * N_ALL;    // 4096
    const int RE = B * N_REL;    // 16384
    const int aggz_f4 = 3 * RN * NF / 4;   // float4 count over the 3 agg buffers

    prep<<<PREP_TOTAL, 256, 0, stream>>>(Rr, Rs, rr, rs, d, wt, wt_total,
                                         state, attrs, action, den, phys, P,
                                         agg3, aggz_f4);
    build_relinputs<<<(RE + 255) / 256, 256, 0, stream>>>(P, attrs, p_instance, rr, rs, RI);

    f_enc<32><<<RN / 64, 256, 0, stream>>>(P, wt + d.cum[0], wt + d.cum[1], wt + d.cum[2],
                                           pe_b0, pe_b1, pe_b2, penc);
    f_enc<64><<<RE / 64, 256, 0, stream>>>(RI, wt + d.cum[3], wt + d.cum[4], wt + d.cum[5],
                                           re_b0, re_b1, re_b2, relenc);

    const u16* effin = penc;
    u16* outbuf[3] = {effA, effB, effA};
    for (int s = 0; s < 3; ++s) {
        float* agg = agg3 + (size_t)s * RN * NF;
        g1_rel<<<RE / 32, 256, 0, stream>>>(relenc, effin, wt + d.cum[7], rp_b, rr, rs, agg);
        g2_part<<<RN / 32, 256, 0, stream>>>(penc, agg, wt + d.cum[6], pp_b, effin, outbuf[s]);
        effin = outbuf[s];
    }

    f_np<<<RN / 64, 256, 0, stream>>>(effin, wt + d.cum[8], wt + d.cum[9],
                                      np_b0, np_b1, np_W2, np_b2, state, (float*)d_out);
}

// Round 4
// 158.338 us; speedup vs baseline: 5.2479x; 1.0691x over previous
//
#include <hip/hip_runtime.h>

#define B 2
#define N_P 2000
#define N_ALL 2048
#define N_REL 8192
#define N_INST 8
#define NF 128

typedef unsigned short u16;
typedef __attribute__((ext_vector_type(8))) short bf16x8;
typedef __attribute__((ext_vector_type(4))) float f32x4;

__device__ __forceinline__ u16 f2bf(float f) {
    union { float f; unsigned u; } v; v.f = f;
    unsigned r = v.u + 0x7FFFu + ((v.u >> 16) & 1u);
    return (u16)(r >> 16);
}
__device__ __forceinline__ float bf2f(u16 h) {
    union { unsigned u; float f; } v; v.u = ((unsigned)h) << 16; return v.f;
}

#define MFMA16(a, b, c) __builtin_amdgcn_mfma_f32_16x16x32_bf16((a), (b), (c), 0, 0, 0)

struct WtCvt {
    const float* src[10];
    int K[10];
    int Kpad[10];
    int cum[11];
};

// ---------------------------------------------------------------------------
// PREP kernel, block-ranged fusion:
//   [0, 2048):      persistent one-hot scan — 8192 waves, 4 rows/wave,
//                   2-row software pipeline (continuous load streams)
//   [2048, 2800):   weight convert fp32 [K][128] -> bf16 [128][Kpad]
//   [2800, 2816):   build p_inputs bf16 [B*N_ALL][32]
//   [2816, 4352):   zero 3 agg buffers
// ---------------------------------------------------------------------------
#define PREP_SCAN_BLKS 2048
#define PREP_CVT_BLKS  752
#define PREP_PIN_BLKS  16
#define PREP_ZERO_BLKS 1536
#define PREP_TOTAL (PREP_SCAN_BLKS + PREP_CVT_BLKS + PREP_PIN_BLKS + PREP_ZERO_BLKS)

__global__ __launch_bounds__(256) void prep(
    const float* __restrict__ Rr, const float* __restrict__ Rs,
    int* __restrict__ rr, int* __restrict__ rs,
    WtCvt d, u16* __restrict__ wt, int wt_total,
    const float* __restrict__ state, const float* __restrict__ attrs,
    const float* __restrict__ action, const float* __restrict__ den,
    const float* __restrict__ phys, u16* __restrict__ P,
    float* __restrict__ aggz, int aggz_f4)
{
    int blk = blockIdx.x;
    if (blk < PREP_SCAN_BLKS) {
        int gw = blk * 4 + (threadIdx.x >> 6);   // 0..8191, 4 rows each
        int lane = threadIdx.x & 63;
        #pragma unroll
        for (int p = 0; p < 2; ++p) {
            int r0 = gw * 4 + p * 2;             // pair of rows, same matrix
            const float* bp = (r0 < 16384) ? (Rr + (size_t)r0 * N_ALL)
                                           : (Rs + (size_t)(r0 - 16384) * N_ALL);
            const float4* s0 = reinterpret_cast<const float4*>(bp);
            const float4* s1 = reinterpret_cast<const float4*>(bp + N_ALL);
            float4 a[8], b[8];
            #pragma unroll
            for (int i = 0; i < 8; ++i) a[i] = s0[lane + 64 * i];
            #pragma unroll
            for (int i = 0; i < 8; ++i) b[i] = s1[lane + 64 * i];
            int f0 = -1, f1 = -1;
            #pragma unroll
            for (int i = 0; i < 8; ++i) {
                int bi = (lane + 64 * i) * 4;
                if (a[i].x != 0.f) f0 = bi;
                if (a[i].y != 0.f) f0 = bi + 1;
                if (a[i].z != 0.f) f0 = bi + 2;
                if (a[i].w != 0.f) f0 = bi + 3;
                if (b[i].x != 0.f) f1 = bi;
                if (b[i].y != 0.f) f1 = bi + 1;
                if (b[i].z != 0.f) f1 = bi + 2;
                if (b[i].w != 0.f) f1 = bi + 3;
            }
            #pragma unroll
            for (int off = 32; off; off >>= 1) {
                f0 = max(f0, __shfl_xor(f0, off));
                f1 = max(f1, __shfl_xor(f1, off));
            }
            if (lane == 0) {
                int* dst = (r0 < 16384) ? rr : rs;
                int e = r0 & 16383;
                dst[e] = f0;
                dst[e + 1] = f1;
            }
        }
        return;
    }
    blk -= PREP_SCAN_BLKS;
    if (blk < PREP_CVT_BLKS) {
        int t = blk * 256 + threadIdx.x;
        if (t >= wt_total) return;
        int m = 0;
        while (t >= d.cum[m + 1]) m++;
        int loc = t - d.cum[m];
        int Kp = d.Kpad[m];
        int c = loc / Kp, k = loc - c * Kp;
        float v = (k < d.K[m]) ? d.src[m][(size_t)k * NF + c] : 0.f;
        wt[t] = f2bf(v);
        return;
    }
    blk -= PREP_CVT_BLKS;
    if (blk < PREP_PIN_BLKS) {
        int t = blk * 256 + threadIdx.x;
        if (t >= B * N_ALL) return;
        int b = t >> 11, n = t & 2047;
        float o[19];
        o[0] = attrs[t * 2]; o[1] = attrs[t * 2 + 1];
        #pragma unroll
        for (int h = 0; h < 3; ++h)
            #pragma unroll
            for (int c = 0; c < 3; ++c)
                o[2 + h * 3 + c] = state[(((size_t)b * 4 + h + 1) * N_ALL + n) * 3 + c]
                                 - state[(((size_t)b * 4 + h)     * N_ALL + n) * 3 + c];
        #pragma unroll
        for (int c = 0; c < 3; ++c)
            o[11 + c] = state[(((size_t)b * 4 + 3) * N_ALL + n) * 3 + c];
        o[14] = (n < N_P) ? phys[b] : 0.f;
        #pragma unroll
        for (int c = 0; c < 3; ++c) o[15 + c] = action[t * 3 + c];
        o[18] = (n < N_P) ? den[b] : 0.f;
        u16* dst = P + (size_t)t * 32;
        #pragma unroll
        for (int k = 0; k < 19; ++k) dst[k] = f2bf(o[k]);
        #pragma unroll
        for (int k = 19; k < 32; ++k) dst[k] = 0;
        return;
    }
    blk -= PREP_PIN_BLKS;
    {
        int t = blk * 256 + threadIdx.x;
        if (t < aggz_f4) {
            float4 z = {0.f, 0.f, 0.f, 0.f};
            reinterpret_cast<float4*>(aggz)[t] = z;
        }
    }
}

// ---------------------------------------------------------------------------
// Shared 3-layer MLP body (wave = 16 rows x 128 cols), layer-0 A from global
// (ALDS=false, stride K0) or from swizzled LDS tile ri (ALDS=true).
// ---------------------------------------------------------------------------
template<int K0, bool ALDS>
__device__ __forceinline__ void enc_body(
    const u16* __restrict__ Xg, const u16* ri,
    const u16* __restrict__ wt0, const u16* __restrict__ wt1, const u16* __restrict__ wt2,
    const float* __restrict__ b0, const float* __restrict__ b1, const float* __restrict__ b2,
    u16* __restrict__ Y, int rbase, int w, int lane, u16* T0, u16* T1)
{
    int r16 = lane & 15, g4 = lane >> 4;
    f32x4 zero = {0.f, 0.f, 0.f, 0.f};
    f32x4 acc[8];
    #pragma unroll
    for (int cf = 0; cf < 8; ++cf) acc[cf] = zero;
    #pragma unroll
    for (int kf = 0; kf < K0 / 32; ++kf) {
        int kcol = kf * 32 + g4 * 8;
        bf16x8 a;
        if (ALDS) {
            int lr = w * 16 + r16;
            a = *reinterpret_cast<const bf16x8*>(&ri[lr * K0 + (kcol ^ ((lr & 7) << 3))]);
        } else {
            a = *reinterpret_cast<const bf16x8*>(Xg + (size_t)(rbase + r16) * K0 + kcol);
        }
        #pragma unroll
        for (int cf = 0; cf < 8; ++cf) {
            bf16x8 bv = *reinterpret_cast<const bf16x8*>(wt0 + (size_t)(cf * 16 + r16) * K0 + kcol);
            acc[cf] = MFMA16(a, bv, acc[cf]);
        }
    }
    #pragma unroll
    for (int cf = 0; cf < 8; ++cf) {
        float bv = b0[cf * 16 + r16];
        #pragma unroll
        for (int i = 0; i < 4; ++i) {
            int row = g4 * 4 + i, col = cf * 16 + r16;
            T0[row * NF + (col ^ ((row & 7) << 3))] = f2bf(fmaxf(acc[cf][i] + bv, 0.f));
        }
    }
    #pragma unroll
    for (int cf = 0; cf < 8; ++cf) acc[cf] = zero;
    #pragma unroll
    for (int kf = 0; kf < 4; ++kf) {
        int kcol = kf * 32 + g4 * 8;
        bf16x8 a = *reinterpret_cast<const bf16x8*>(&T0[r16 * NF + (kcol ^ ((r16 & 7) << 3))]);
        #pragma unroll
        for (int cf = 0; cf < 8; ++cf) {
            bf16x8 bv = *reinterpret_cast<const bf16x8*>(wt1 + (size_t)(cf * 16 + r16) * NF + kcol);
            acc[cf] = MFMA16(a, bv, acc[cf]);
        }
    }
    #pragma unroll
    for (int cf = 0; cf < 8; ++cf) {
        float bv = b1[cf * 16 + r16];
        #pragma unroll
        for (int i = 0; i < 4; ++i) {
            int row = g4 * 4 + i, col = cf * 16 + r16;
            T1[row * NF + (col ^ ((row & 7) << 3))] = f2bf(fmaxf(acc[cf][i] + bv, 0.f));
        }
    }
    #pragma unroll
    for (int cf = 0; cf < 8; ++cf) acc[cf] = zero;
    #pragma unroll
    for (int kf = 0; kf < 4; ++kf) {
        int kcol = kf * 32 + g4 * 8;
        bf16x8 a = *reinterpret_cast<const bf16x8*>(&T1[r16 * NF + (kcol ^ ((r16 & 7) << 3))]);
        #pragma unroll
        for (int cf = 0; cf < 8; ++cf) {
            bf16x8 bv = *reinterpret_cast<const bf16x8*>(wt2 + (size_t)(cf * 16 + r16) * NF + kcol);
            acc[cf] = MFMA16(a, bv, acc[cf]);
        }
    }
    #pragma unroll
    for (int cf = 0; cf < 8; ++cf) {
        float bv = b2[cf * 16 + r16];
        #pragma unroll
        for (int i = 0; i < 4; ++i) {
            int row = rbase + g4 * 4 + i;
            Y[(size_t)row * NF + cf * 16 + r16] = f2bf(fmaxf(acc[cf][i] + bv, 0.f));
        }
    }
}

// ---------------------------------------------------------------------------
// ENC kernel: blocks [0,64) particle encoder; [64,320) relation encoder with
// in-kernel rel_inputs tile build (no global RI round-trip).
// ---------------------------------------------------------------------------
__global__ __launch_bounds__(256) void enc(
    const u16* __restrict__ P,
    const u16* __restrict__ wp0, const u16* __restrict__ wp1, const u16* __restrict__ wp2,
    const float* __restrict__ pb0, const float* __restrict__ pb1, const float* __restrict__ pb2,
    const u16* __restrict__ wr0, const u16* __restrict__ wr1, const u16* __restrict__ wr2,
    const float* __restrict__ rb0, const float* __restrict__ rb1, const float* __restrict__ rb2,
    const float* __restrict__ attrs, const float* __restrict__ p_inst,
    const int* __restrict__ rr, const int* __restrict__ rs,
    u16* __restrict__ penc, u16* __restrict__ relenc)
{
    __shared__ u16 ri[64 * 64];
    __shared__ u16 tile[4][2][16 * NF];
    int w = threadIdx.x >> 6, lane = threadIdx.x & 63;
    int blk = blockIdx.x;
    if (blk < 64) {
        int rbase = blk * 64 + w * 16;
        enc_body<32, false>(P, nullptr, wp0, wp1, wp2, pb0, pb1, pb2,
                            penc, rbase, w, lane, tile[w][0], tile[w][1]);
        return;
    }
    int blk2 = blk - 64;
    {   // build rel_inputs tile: 4 threads per row, 16 cols each
        int row = threadIdx.x >> 2;
        int q = threadIdx.x & 3;
        int grow = blk2 * 64 + row;
        int b = grow >> 13;
        int ir = rr[grow], is_ = rs[grow];
        const u16* pr = P + ((size_t)(b << 11) + ir) * 32;
        const u16* ps = P + ((size_t)(b << 11) + is_) * 32;
        float gd = 0.f;
        if (q == 2) {
            #pragma unroll
            for (int k = 0; k < N_INST; ++k) {
                float gr = (ir < N_P) ? p_inst[((size_t)b * N_P + ir) * N_INST + k] : 0.f;
                float gs = (is_ < N_P) ? p_inst[((size_t)b * N_P + is_) * N_INST + k] : 0.f;
                gd += fabsf(gr - gs);
            }
        }
        #pragma unroll
        for (int j = 0; j < 16; ++j) {
            int c = q * 16 + j;
            u16 hv;
            if (c < 19)       hv = pr[c];
            else if (c < 38)  hv = ps[c - 19];
            else if (c < 40)  hv = f2bf(attrs[((size_t)(b << 11) + ir) * 2 + (c - 38)]);
            else if (c < 42)  hv = f2bf(attrs[((size_t)(b << 11) + is_) * 2 + (c - 40)]);
            else if (c == 42) hv = f2bf(gd);
            else if (c < 55)  hv = f2bf(bf2f(pr[c - 41]) - bf2f(ps[c - 41]));
            else if (c == 55) hv = f2bf(bf2f(pr[18]) - bf2f(ps[18]));
            else              hv = 0;
            ri[row * 64 + (c ^ ((row & 7) << 3))] = hv;
        }
    }
    __syncthreads();
    int rbase = blk2 * 64 + w * 16;
    enc_body<64, true>(nullptr, ri, wr0, wr1, wr2, rb0, rb1, rb2,
                       relenc, rbase, w, lane, tile[w][0], tile[w][1]);
}

// ---------------------------------------------------------------------------
// G1: relation propagator, K=384 = [relenc | eff[rr] | eff[rs]], fused scatter
// ---------------------------------------------------------------------------
__global__ __launch_bounds__(256) void g1_rel(
    const u16* __restrict__ relenc, const u16* __restrict__ eff,
    const u16* __restrict__ wt_rp, const float* __restrict__ rp_b,
    const int* __restrict__ rr, const int* __restrict__ rs,
    float* __restrict__ agg)
{
    int lane = threadIdx.x & 63;
    int gw = blockIdx.x * 4 + (threadIdx.x >> 6);
    int rt = gw >> 2, ct = gw & 3;
    int r16 = lane & 15, g4 = lane >> 4;
    int rbase = rt * 32, cbase = ct * 32;

    int idxr[2], idxs[2];
    #pragma unroll
    for (int rf = 0; rf < 2; ++rf) {
        int row = rbase + rf * 16 + r16;
        int b = row >> 13;
        idxr[rf] = (b << 11) + rr[row];
        idxs[rf] = (b << 11) + rs[row];
    }
    f32x4 zero = {0.f, 0.f, 0.f, 0.f};
    f32x4 acc[2][2] = {{zero, zero}, {zero, zero}};

    #pragma unroll
    for (int kf = 0; kf < 12; ++kf) {
        int kcol = kf * 32 + g4 * 8;
        bf16x8 a[2];
        #pragma unroll
        for (int rf = 0; rf < 2; ++rf) {
            int row = rbase + rf * 16 + r16;
            const u16* ap;
            if (kf < 4)      ap = relenc + (size_t)row * NF + kcol;
            else if (kf < 8) ap = eff + (size_t)idxr[rf] * NF + (kcol - NF);
            else             ap = eff + (size_t)idxs[rf] * NF + (kcol - 2 * NF);
            a[rf] = *reinterpret_cast<const bf16x8*>(ap);
        }
        #pragma unroll
        for (int cf = 0; cf < 2; ++cf) {
            bf16x8 bv = *reinterpret_cast<const bf16x8*>(wt_rp + (size_t)(cbase + cf * 16 + r16) * 384 + kcol);
            #pragma unroll
            for (int rf = 0; rf < 2; ++rf)
                acc[rf][cf] = MFMA16(a[rf], bv, acc[rf][cf]);
        }
    }
    #pragma unroll
    for (int rf = 0; rf < 2; ++rf)
        #pragma unroll
        for (int i = 0; i < 4; ++i) {
            int row = rbase + rf * 16 + g4 * 4 + i;
            int dstn = ((row >> 13) << 11) + rr[row];
            float* ap = agg + (size_t)dstn * NF;
            #pragma unroll
            for (int cf = 0; cf < 2; ++cf) {
                int col = cbase + cf * 16 + r16;
                float v = fmaxf(acc[rf][cf][i] + rp_b[col], 0.f);
                atomicAdd(ap + col, v);
            }
        }
}

// ---------------------------------------------------------------------------
// G2: particle propagator. LAST=1 fuses the predictor MLP (np0/np1/np2+clamp
// +state residual) — block owns complete 32 rows of eff.
// ---------------------------------------------------------------------------
template<int LAST>
__global__ __launch_bounds__(256) void g2_part(
    const u16* __restrict__ penc, const float* __restrict__ agg,
    const u16* __restrict__ wt_pp, const float* __restrict__ pp_b,
    const u16* __restrict__ eff_prev, u16* __restrict__ eff_out,
    const u16* __restrict__ wn0, const u16* __restrict__ wn1,
    const float* __restrict__ nb0, const float* __restrict__ nb1,
    const float* __restrict__ W2, const float* __restrict__ b2v,
    const float* __restrict__ state, float* __restrict__ out)
{
    __shared__ u16 E[32 * NF];
    __shared__ u16 npt[2][2][16 * NF];
    int lane = threadIdx.x & 63;
    int w = threadIdx.x >> 6;
    int blk = blockIdx.x;
    int r16 = lane & 15, g4 = lane >> 4;
    int rbase = blk * 32, cbase = w * 32;
    f32x4 zero = {0.f, 0.f, 0.f, 0.f};
    f32x4 acc[2][2] = {{zero, zero}, {zero, zero}};

    #pragma unroll
    for (int kf = 0; kf < 8; ++kf) {
        int kcol = kf * 32 + g4 * 8;
        bf16x8 a[2];
        #pragma unroll
        for (int rf = 0; rf < 2; ++rf) {
            int row = rbase + rf * 16 + r16;
            if (kf < 4) {
                a[rf] = *reinterpret_cast<const bf16x8*>(penc + (size_t)row * NF + kcol);
            } else {
                const float* ap = agg + (size_t)row * NF + (kcol - NF);
                float4 lo = *reinterpret_cast<const float4*>(ap);
                float4 hi = *reinterpret_cast<const float4*>(ap + 4);
                bf16x8 t;
                t[0] = (short)f2bf(lo.x); t[1] = (short)f2bf(lo.y);
                t[2] = (short)f2bf(lo.z); t[3] = (short)f2bf(lo.w);
                t[4] = (short)f2bf(hi.x); t[5] = (short)f2bf(hi.y);
                t[6] = (short)f2bf(hi.z); t[7] = (short)f2bf(hi.w);
                a[rf] = t;
            }
        }
        #pragma unroll
        for (int cf = 0; cf < 2; ++cf) {
            bf16x8 bv = *reinterpret_cast<const bf16x8*>(wt_pp + (size_t)(cbase + cf * 16 + r16) * 256 + kcol);
            #pragma unroll
            for (int rf = 0; rf < 2; ++rf)
                acc[rf][cf] = MFMA16(a[rf], bv, acc[rf][cf]);
        }
    }
    #pragma unroll
    for (int rf = 0; rf < 2; ++rf)
        #pragma unroll
        for (int i = 0; i < 4; ++i) {
            int lrow = rf * 16 + g4 * 4 + i;
            int row = rbase + lrow;
            #pragma unroll
            for (int cf = 0; cf < 2; ++cf) {
                int col = cbase + cf * 16 + r16;
                float v = acc[rf][cf][i] + pp_b[col] + bf2f(eff_prev[(size_t)row * NF + col]);
                u16 hv = f2bf(fmaxf(v, 0.f));
                if (LAST) E[lrow * NF + (col ^ ((lrow & 7) << 3))] = hv;
                else      eff_out[(size_t)row * NF + col] = hv;
            }
        }
    if (LAST) {
        __syncthreads();
        if (w < 2) {
            // predictor MLP on rows rbase + w*16 + [0,16)
            f32x4 acc2[8];
            #pragma unroll
            for (int cf = 0; cf < 8; ++cf) acc2[cf] = zero;
            #pragma unroll
            for (int kf = 0; kf < 4; ++kf) {
                int kcol = kf * 32 + g4 * 8;
                int lr = w * 16 + r16;
                bf16x8 a = *reinterpret_cast<const bf16x8*>(&E[lr * NF + (kcol ^ ((lr & 7) << 3))]);
                #pragma unroll
                for (int cf = 0; cf < 8; ++cf) {
                    bf16x8 bv = *reinterpret_cast<const bf16x8*>(wn0 + (size_t)(cf * 16 + r16) * NF + kcol);
                    acc2[cf] = MFMA16(a, bv, acc2[cf]);
                }
            }
            u16* T0 = npt[w][0];
            #pragma unroll
            for (int cf = 0; cf < 8; ++cf) {
                float bv = nb0[cf * 16 + r16];
                #pragma unroll
                for (int i = 0; i < 4; ++i) {
                    int row = g4 * 4 + i, col = cf * 16 + r16;
                    T0[row * NF + (col ^ ((row & 7) << 3))] = f2bf(fmaxf(acc2[cf][i] + bv, 0.f));
                }
            }
            #pragma unroll
            for (int cf = 0; cf < 8; ++cf) acc2[cf] = zero;
            #pragma unroll
            for (int kf = 0; kf < 4; ++kf) {
                int kcol = kf * 32 + g4 * 8;
                bf16x8 a = *reinterpret_cast<const bf16x8*>(&T0[r16 * NF + (kcol ^ ((r16 & 7) << 3))]);
                #pragma unroll
                for (int cf = 0; cf < 8; ++cf) {
                    bf16x8 bv = *reinterpret_cast<const bf16x8*>(wn1 + (size_t)(cf * 16 + r16) * NF + kcol);
                    acc2[cf] = MFMA16(a, bv, acc2[cf]);
                }
            }
            u16* T1 = npt[w][1];
            #pragma unroll
            for (int cf = 0; cf < 8; ++cf) {
                float bv = nb1[cf * 16 + r16];
                #pragma unroll
                for (int i = 0; i < 4; ++i) {
                    int row = g4 * 4 + i, col = cf * 16 + r16;
                    T1[row * NF + (col ^ ((row & 7) << 3))] = f2bf(fmaxf(acc2[cf][i] + bv, 0.f));
                }
            }
            if (g4 < 3) {
                int grow = rbase + w * 16 + r16;
                int b = grow >> 11, n = grow & 2047;
                if (n < N_P) {
                    float s = b2v[g4];
                    for (int k = 0; k < NF; ++k)
                        s += bf2f(T1[r16 * NF + (k ^ ((r16 & 7) << 3))]) * W2[k * 3 + g4];
                    s = fminf(fmaxf(s, -100.f), 100.f);
                    out[((size_t)b * N_P + n) * 3 + g4] =
                        s + state[(((size_t)b * 4 + 3) * N_ALL + n) * 3 + g4];
                }
            }
        }
    }
}

// ---------------------------------------------------------------------------
extern "C" void kernel_launch(void* const* d_in, const int* in_sizes, int n_in,
                              void* d_out, int out_size, void* d_ws, size_t ws_size,
                              hipStream_t stream) {
    (void)in_sizes; (void)n_in; (void)out_size; (void)ws_size;
    const float* state      = (const float*)d_in[0];
    const float* attrs      = (const float*)d_in[1];
    const float* Rr         = (const float*)d_in[2];
    const float* Rs         = (const float*)d_in[3];
    const float* p_instance = (const float*)d_in[4];
    const float* action     = (const float*)d_in[5];
    const float* den        = (const float*)d_in[6];
    const float* phys       = (const float*)d_in[7];
    const float* pe_W0 = (const float*)d_in[8];  const float* pe_b0 = (const float*)d_in[9];
    const float* pe_W1 = (const float*)d_in[10]; const float* pe_b1 = (const float*)d_in[11];
    const float* pe_W2 = (const float*)d_in[12]; const float* pe_b2 = (const float*)d_in[13];
    const float* re_W0 = (const float*)d_in[14]; const float* re_b0 = (const float*)d_in[15];
    const float* re_W1 = (const float*)d_in[16]; const float* re_b1 = (const float*)d_in[17];
    const float* re_W2 = (const float*)d_in[18]; const float* re_b2 = (const float*)d_in[19];
    const float* pp_W  = (const float*)d_in[20]; const float* pp_b  = (const float*)d_in[21];
    const float* rp_W  = (const float*)d_in[22]; const float* rp_b  = (const float*)d_in[23];
    const float* np_W0 = (const float*)d_in[24]; const float* np_b0 = (const float*)d_in[25];
    const float* np_W1 = (const float*)d_in[26]; const float* np_b1 = (const float*)d_in[27];
    const float* np_W2 = (const float*)d_in[28]; const float* np_b2 = (const float*)d_in[29];

    char* base = (char*)d_ws;
    size_t off = 0;
    auto alloc = [&](size_t bytes) -> void* {
        off = (off + 255) & ~(size_t)255;
        void* p = base + off; off += bytes; return p;
    };
    int* rr      = (int*)alloc(B * N_REL * 4);
    int* rs      = (int*)alloc(B * N_REL * 4);
    u16* P       = (u16*)alloc((size_t)B * N_ALL * 32 * 2);
    u16* penc    = (u16*)alloc((size_t)B * N_ALL * NF * 2);
    u16* relenc  = (u16*)alloc((size_t)B * N_REL * NF * 2);
    u16* effA    = (u16*)alloc((size_t)B * N_ALL * NF * 2);
    u16* effB    = (u16*)alloc((size_t)B * N_ALL * NF * 2);
    float* agg3  = (float*)alloc((size_t)3 * B * N_ALL * NF * 4);

    WtCvt d;
    const float* srcs[10] = {pe_W0, pe_W1, pe_W2, re_W0, re_W1, re_W2, pp_W, rp_W, np_W0, np_W1};
    const int Ks[10]  = {19, 128, 128, 56, 128, 128, 256, 384, 128, 128};
    const int Kps[10] = {32, 128, 128, 64, 128, 128, 256, 384, 128, 128};
    d.cum[0] = 0;
    for (int i = 0; i < 10; ++i) {
        d.src[i] = srcs[i]; d.K[i] = Ks[i]; d.Kpad[i] = Kps[i];
        d.cum[i + 1] = d.cum[i] + NF * Kps[i];
    }
    int wt_total = d.cum[10];
    u16* wt = (u16*)alloc((size_t)wt_total * 2);

    const int RN = B * N_ALL;    // 4096
    const int RE = B * N_REL;    // 16384
    const int aggz_f4 = 3 * RN * NF / 4;

    prep<<<PREP_TOTAL, 256, 0, stream>>>(Rr, Rs, rr, rs, d, wt, wt_total,
                                         state, attrs, action, den, phys, P,
                                         agg3, aggz_f4);

    enc<<<64 + RE / 64, 256, 0, stream>>>(P,
        wt + d.cum[0], wt + d.cum[1], wt + d.cum[2], pe_b0, pe_b1, pe_b2,
        wt + d.cum[3], wt + d.cum[4], wt + d.cum[5], re_b0, re_b1, re_b2,
        attrs, p_instance, rr, rs, penc, relenc);

    const u16* effin = penc;
    u16* outbuf[3] = {effA, effB, effA};
    for (int s = 0; s < 3; ++s) {
        float* agg = agg3 + (size_t)s * RN * NF;
        g1_rel<<<RE / 32, 256, 0, stream>>>(relenc, effin, wt + d.cum[7], rp_b, rr, rs, agg);
        if (s < 2)
            g2_part<0><<<RN / 32, 256, 0, stream>>>(penc, agg, wt + d.cum[6], pp_b, effin, outbuf[s],
                wt + d.cum[8], wt + d.cum[9], np_b0, np_b1, np_W2, np_b2, state, (float*)d_out);
        else
            g2_part<1><<<RN / 32, 256, 0, stream>>>(penc, agg, wt + d.cum[6], pp_b, effin, outbuf[s],
                wt + d.cum[8], wt + d.cum[9], np_b0, np_b1, np_W2, np_b2, state, (float*)d_out);
        effin = outbuf[s];
    }
}